// Round 8
// baseline (693.619 us; speedup 1.0000x reference)
//
#include <hip/hip_runtime.h>
#include <stdint.h>

#define NROW 256
#define NV   128000
#define NV4  (NV / 4)
#define HALF_F4 (NV4 / 2)       // 16000 float4 per half-row
#define NBIN 7680
#define NCH  8
#define BLO  0x42300000u        // bits of 44.0f
#define BSH  10
#define GCAP 4096
#define LOG2E 1.44269504088896340736f
#define TPB  1024
#define LCAP 2048
#define RMARG 1.005f
#define T_HI_BITS 0x42A7FFFFu   // ~83.99999 -> bin <= 7679
#define NG   2048               // select radix groups
#define TCAP 2048               // tie capacity
#define EPT4 (GCAP / TPB)       // 4 elements per thread in select phase

// ---- workspace layout (bytes) ----
#define PART_BYTES ((size_t)512 * (NBIN / 2) * 4)        // 7,864,320 (packed u16 pairs)
#define WS_PART   0
#define WS_ZQ     (PART_BYTES)                            // 256*8 f32 (2 slots/row used)
#define WS_SAB    (WS_ZQ   + (size_t)NROW * 8 * 4)
#define WS_GCNT   (WS_SAB  + (size_t)NROW * 8 * 4)
#define WS_BEST   (WS_GCNT + (size_t)NROW * 8 * 4)
#define WS_PARAMS (WS_BEST + (size_t)NROW * 8)
#define WS_GATHER (WS_PARAMS + (size_t)NROW * 16)
#define WS_DONE   (WS_GATHER + (size_t)NROW * GCAP * 8)
#define WS_NEEDED (WS_DONE + 2048)
// gu overlays partials (fully consumed by A's scan before B writes gu)
#define WS_GU     WS_PART

struct RowParams { int bl; int bh; float P; int pad; };

__device__ __forceinline__ unsigned fenc(float f) {
    unsigned b = __float_as_uint(f);
    return b ^ (((unsigned)((int)b >> 31)) | 0x80000000u);
}
__device__ __forceinline__ float fdec(unsigned e) {
    unsigned m = ((int)e >= 0) ? 0xFFFFFFFFu : 0x80000000u;
    return __uint_as_float(e ^ m);
}

// monotone race key: log2(p/noise) + const = s*log2e - log2(-log2 u) + const
__device__ __forceinline__ unsigned long long race_key(float s, float u, unsigned idx) {
    float nl  = -__builtin_amdgcn_logf(u);
    float l2n = __builtin_amdgcn_logf(nl);
    float keyf = fmaf(s, LOG2E, -l2n);
    return ((unsigned long long)fenc(keyf) << 32) | (unsigned)(~idx);
}

__device__ __forceinline__ int bin_of(float s) {
    float tc = fminf(fmaxf(s + 64.0f, 44.0f), __uint_as_float(T_HI_BITS));
    return (int)((__float_as_uint(tc) - BLO) >> BSH);
}

__device__ __forceinline__ float qval(float s) {       // exp(s) * 2^-20
    return __builtin_amdgcn_exp2f(fmaf(s, LOG2E, -20.0f));
}

__device__ __forceinline__ float cmid(int b) {         // geometric-mid mass of bin b
    float tlo = __uint_as_float(BLO + ((unsigned)b << BSH));
    float thi = __uint_as_float(BLO + ((unsigned)(b + 1) << BSH));
    float tm = 0.5f * (tlo + thi);
    return __builtin_amdgcn_exp2f(fmaf(tm - 64.0f, LOG2E, -20.0f));
}

// ---------------- init: zero the per-row tickets ----------------------------
__global__ void k_init(unsigned* __restrict__ doneA, unsigned* __restrict__ doneB)
{
    const int t = threadIdx.x;
    if (t < NROW) doneA[t] = 0u;
    else if (t < 2 * NROW) doneB[t - NROW] = 0u;
}

// ======= Kernel A: histogram + Zq streaming; last block per row scans =======
__global__ __launch_bounds__(TPB)
void kA(const float* __restrict__ logits, const float* __restrict__ temps,
        const float* __restrict__ topps,
        unsigned* __restrict__ partials, float* __restrict__ zq,
        RowParams* __restrict__ params,
        unsigned int* __restrict__ gcnt, unsigned long long* __restrict__ best,
        unsigned* __restrict__ doneA)
{
    __shared__ __align__(16) char smem[61440];
    unsigned* lh = (unsigned*)smem;            // [NBIN] phase-1 counts
    float*    qm = (float*)(smem + 30720);     // [NBIN] phase-2 mass suffix
    float*    qc = (float*)smem;               // [NBIN] phase-2 count suffix (aliases lh)
    __shared__ float wred[16];
    __shared__ float wtm[16], wtc[16], wsm[16], wsc[16];
    __shared__ int shbH, shbL, shbLp;
    __shared__ unsigned sh_last;

    const int row = blockIdx.x >> 1;
    const int sl  = blockIdx.x & 1;
    const int tid = threadIdx.x;
    for (int b = tid; b < NBIN; b += TPB) lh[b] = 0u;
    if (tid == 0 && sl == 0) {                 // init for B (stream-ordered)
        gcnt[row * 8] = 0u;
        best[row] = 0ull;
    }
    __syncthreads();
    const float invT = 1.0f / temps[row];
    const float4* __restrict__ l4 =
        (const float4*)(logits + (size_t)row * NV) + sl * HALF_F4;
    float zacc = 0.0f;

    auto h4 = [&](float4 x, bool valid) {
        float xs[4] = {x.x, x.y, x.z, x.w};
        #pragma unroll
        for (int c = 0; c < 4; ++c) {
            float s = xs[c] * invT;
            if (valid) {
                atomicAdd(&lh[bin_of(s)], 1u);
                zacc += qval(s);
            }
        }
    };
    for (int v = tid; v < HALF_F4; v += 4 * TPB) {
        int v1 = v + TPB, v2 = v + 2 * TPB, v3 = v + 3 * TPB;
        bool g1 = v1 < HALF_F4, g2 = v2 < HALF_F4, g3 = v3 < HALF_F4;
        float4 x0 = l4[v];
        float4 x1 = l4[g1 ? v1 : v];
        float4 x2 = l4[g2 ? v2 : v];
        float4 x3 = l4[g3 ? v3 : v];
        h4(x0, true); h4(x1, g1); h4(x2, g2); h4(x3, g3);
    }
    #pragma unroll
    for (int o = 32; o > 0; o >>= 1) zacc += __shfl_down(zacc, o, 64);
    if ((tid & 63) == 0) wred[tid >> 6] = zacc;
    __syncthreads();
    if (tid == 0) {
        float z = 0.0f;
        #pragma unroll
        for (int w = 0; w < TPB / 64; ++w) z += wred[w];
        zq[row * 8 + sl] = z;
    }
    unsigned* __restrict__ pc = partials + (size_t)blockIdx.x * (NBIN / 2);
    for (int pb = tid; pb < NBIN / 2; pb += TPB)
        pc[pb] = (lh[2 * pb] & 0xFFFFu) | (lh[2 * pb + 1] << 16);

    // -------- ticket: last of the row's 2 blocks runs the scan --------------
    __threadfence();
    if (tid == 0)
        sh_last = __hip_atomic_fetch_add(&doneA[row], 1u, __ATOMIC_ACQ_REL,
                                         __HIP_MEMORY_SCOPE_AGENT);
    __syncthreads();
    if (sh_last == 0u) return;
    __threadfence();

    // -------- scan phase (one block, row-wide): merge, suffix, window -------
    const unsigned* __restrict__ p0 = partials + (size_t)(row * 2) * (NBIN / 2);
    const unsigned* __restrict__ p1 = p0 + (NBIN / 2);
    for (int pb = tid; pb < NBIN / 2; pb += TPB) {
        unsigned a = p0[pb], b = p1[pb];
        unsigned c0 = (a & 0xFFFFu) + (b & 0xFFFFu);
        unsigned c1 = (a >> 16) + (b >> 16);
        int b0 = 2 * pb, b1 = 2 * pb + 1;
        qc[b0] = (float)c0; qm[b0] = c0 ? (float)c0 * cmid(b0) : 0.0f;
        qc[b1] = (float)c1; qm[b1] = c1 ? (float)c1 * cmid(b1) : 0.0f;
    }
    if (tid == 0) { shbH = NBIN - 1; shbL = 0; }
    __syncthreads();

    const int nown = NBIN / NCH;               // 960
    const int b0 = tid * NCH;
    float chm = 0.0f, chc = 0.0f;
    if (tid < nown) {
        #pragma unroll
        for (int i = 0; i < NCH; ++i) { chm += qm[b0 + i]; chc += qc[b0 + i]; }
    }
    float sm = chm, sc = chc;
    const int lane = tid & 63;
    #pragma unroll
    for (int o = 1; o < 64; o <<= 1) {
        float tm_ = __shfl_down(sm, o, 64);
        float tc_ = __shfl_down(sc, o, 64);
        if (lane + o < 64) { sm += tm_; sc += tc_; }
    }
    if (lane == 0) { wtm[tid >> 6] = sm; wtc[tid >> 6] = sc; }
    __syncthreads();
    if (tid < 16) {
        float em = 0.0f, ec = 0.0f;
        for (int w = tid + 1; w < 16; ++w) { em += wtm[w]; ec += wtc[w]; }
        wsm[tid] = em; wsc[tid] = ec;
    }
    __syncthreads();
    {
        float gm = sm + wsm[tid >> 6];
        float gc = sc + wsc[tid >> 6];
        if (tid < nown) {
            float runm = gm - chm;
            float runc = gc - chc;
            for (int i = NCH - 1; i >= 0; --i) {
                runm += qm[b0 + i]; qm[b0 + i] = runm;
                runc += qc[b0 + i]; qc[b0 + i] = runc;
            }
        }
    }
    __syncthreads();

    const float P = topps[row] * (zq[row * 8] + zq[row * 8 + 1]);
    if (tid < nown) {
        for (int i = 0; i < NCH; ++i) {
            int b = b0 + i;
            float Sb  = qm[b];
            float Sb1 = (b + 1 < NBIN) ? qm[b + 1] : 0.0f;
            if (Sb1 * RMARG <= P) atomicMin(&shbH, b);
            if (Sb > RMARG * P)   atomicMax(&shbL, b);
        }
    }
    __syncthreads();
    const int bH = shbH;
    if (tid == 0) shbLp = bH;
    __syncthreads();
    const float target = (float)GCAP + ((bH + 1 < NBIN) ? qc[bH + 1] : 0.0f);
    const int bL = shbL;
    if (tid < nown) {
        for (int i = 0; i < NCH; ++i) {
            int b = b0 + i;
            if (b >= bL && qc[b] <= target) atomicMin(&shbLp, b);
        }
    }
    __syncthreads();
    if (tid == 0) {
        RowParams rp; rp.bl = shbLp; rp.bh = bH; rp.P = P; rp.pad = 0;
        params[row] = rp;
    }
}

// ======= Kernel B: race+gather streaming; last block per row selects ========
__global__ __launch_bounds__(TPB)
void kB(const float* __restrict__ logits, const float* __restrict__ temps,
        const float* __restrict__ unoise, const RowParams* __restrict__ params,
        unsigned long long* __restrict__ best, unsigned int* __restrict__ gcnt,
        unsigned long long* __restrict__ gather, float* __restrict__ gu,
        float* __restrict__ sab, unsigned* __restrict__ doneB,
        int* __restrict__ out)
{
    __shared__ __align__(16) char smem[49152];
    // race-phase carve
    unsigned long long* stage  = (unsigned long long*)smem;        // 16KB [LCAP]
    unsigned*           stageU = (unsigned*)(smem + 16384);        //  8KB [LCAP]
    // select-phase carve (reuses the same bytes)
    float* ms  = (float*)smem;                                     //  8KB [NG]
    float* ssA = (float*)(smem + 8192);                            //  8KB [NG]
    float* ssB = (float*)(smem + 16384);                           //  8KB [NG]
    unsigned long long* tk = (unsigned long long*)(smem + 24576);  // 16KB [TCAP]
    unsigned*           tu = (unsigned*)(smem + 40960);            //  8KB [TCAP]
    __shared__ unsigned long long wb[16];
    __shared__ float wsab[16];
    __shared__ unsigned int lcnt, sh_base, sh_last;
    __shared__ unsigned long long red_b[16];
    __shared__ float wt[16], we[16];
    __shared__ int sh_gstar, sh_kst;
    __shared__ unsigned sh_kmin, sh_kmax, sh_tn;
    __shared__ float sh_above;
    __shared__ unsigned long long sh_best;

    const int row = blockIdx.x >> 1;
    const int sl  = blockIdx.x & 1;
    const int tid = threadIdx.x;
    if (tid == 0) lcnt = 0u;
    __syncthreads();
    const RowParams rp = params[row];
    const int bl = rp.bl, bh = rp.bh;
    const float invT = 1.0f / temps[row];
    const float4* __restrict__ l4 =
        (const float4*)(logits + (size_t)row * NV) + sl * HALF_F4;
    const float4* __restrict__ u4 =
        (const float4*)(unoise + (size_t)row * NV) + sl * HALF_F4;
    unsigned long long* __restrict__ grow = gather + (size_t)row * GCAP;
    float* __restrict__ gurow = gu + (size_t)row * GCAP;
    unsigned int* __restrict__ gcr = &gcnt[row * 8];
    const int ibase = sl * HALF_F4 * 4;
    unsigned long long mybest = 0ull;
    float sabacc = 0.0f;

    auto proc4 = [&](float4 x, float4 uu, bool valid, int vidx) {
        float xs[4] = {x.x, x.y, x.z, x.w};
        float us[4] = {uu.x, uu.y, uu.z, uu.w};
        #pragma unroll
        for (int c = 0; c < 4; ++c) {
            float s = xs[c] * invT;
            int bin = bin_of(s);
            unsigned idx = (unsigned)(ibase + vidx * 4 + c);
            if (valid && bin > bh) {
                unsigned long long key = race_key(s, us[c], idx);
                if (key > mybest) mybest = key;
                sabacc += qval(s);
            } else if (valid && bin >= bl) {
                unsigned long long ent =
                    ((unsigned long long)fenc(s) << 32) | (unsigned)(~idx);
                unsigned pos = atomicAdd(&lcnt, 1u);
                if (pos < LCAP) { stage[pos] = ent; stageU[pos] = __float_as_uint(us[c]); }
                else {
                    unsigned gp = atomicAdd(gcr, 1u);
                    if (gp < GCAP) { grow[gp] = ent; gurow[gp] = us[c]; }
                }
            }
        }
    };

    for (int v = tid; v < HALF_F4; v += 2 * TPB) {
        int v1 = v + TPB;
        bool g1 = v1 < HALF_F4;
        float4 x0 = l4[v];
        float4 u0 = u4[v];
        float4 x1 = l4[g1 ? v1 : v];
        float4 u1 = u4[g1 ? v1 : v];
        proc4(x0, u0, true, v);
        proc4(x1, u1, g1, v1);
    }
    #pragma unroll
    for (int o = 32; o > 0; o >>= 1) {
        unsigned long long other = __shfl_down(mybest, o, 64);
        if (other > mybest) mybest = other;
        sabacc += __shfl_down(sabacc, o, 64);
    }
    if ((tid & 63) == 0) { wb[tid >> 6] = mybest; wsab[tid >> 6] = sabacc; }
    __syncthreads();
    if (tid == 0) {
        unsigned long long m2 = wb[0];
        float sz = wsab[0];
        #pragma unroll
        for (int w = 1; w < TPB / 64; ++w) {
            if (wb[w] > m2) m2 = wb[w];
            sz += wsab[w];
        }
        if (m2) atomicMax(&best[row], m2);
        sab[row * 8 + sl] = sz;
        unsigned int nn = lcnt; if (nn > LCAP) nn = LCAP;
        sh_base = (nn > 0u) ? atomicAdd(gcr, nn) : 0xFFFFFFF0u;
    }
    __syncthreads();
    {
        unsigned int nn = lcnt; if (nn > LCAP) nn = LCAP;
        unsigned int base = sh_base;
        for (unsigned int i = tid; i < nn; i += TPB) {
            unsigned int p = base + i;
            if (p < GCAP) { grow[p] = stage[i]; gurow[p] = __uint_as_float(stageU[i]); }
        }
    }

    // -------- ticket: last of the row's 2 blocks runs select ----------------
    __threadfence();
    if (tid == 0)
        sh_last = __hip_atomic_fetch_add(&doneB[row], 1u, __ATOMIC_ACQ_REL,
                                         __HIP_MEMORY_SCOPE_AGENT);
    __syncthreads();
    if (sh_last == 0u) return;
    __threadfence();

    // -------- select phase (one block, row-wide) ----------------------------
    unsigned n = gcnt[row * 8]; if (n > GCAP) n = GCAP;
    unsigned long long row_best = best[row];
    if (n == 0) {
        if (tid == 0) out[row] = (int)(~(unsigned)(row_best & 0xFFFFFFFFull));
        return;
    }
    if (tid == 0) {
        sh_best = row_best; sh_gstar = -1; sh_tn = 0u; sh_kst = 0;
        sh_kmin = 0xFFFFFFFFu; sh_kmax = 0u;
    }
    for (int g = tid; g < NG; g += TPB) ms[g] = 0.0f;
    __syncthreads();

    unsigned long long e[EPT4];
    bool val[EPT4];
    unsigned kmn = 0xFFFFFFFFu, kmx = 0u;
    #pragma unroll
    for (int j = 0; j < EPT4; ++j) {
        int p = tid + j * TPB;
        val[j] = (unsigned)p < n;
        e[j] = val[j] ? grow[p] : 0ull;
        if (val[j]) {
            unsigned k = (unsigned)(e[j] >> 32);
            kmn = min(kmn, k); kmx = max(kmx, k);
        }
    }
    atomicMin(&sh_kmin, kmn);
    atomicMax(&sh_kmax, kmx);
    __syncthreads();

    const unsigned kmin = sh_kmin;
    const unsigned span = sh_kmax - kmin;
    const int Lb = 32 - __clz(span);
    const int shft = (Lb > 11) ? (Lb - 11) : 0;
    #pragma unroll
    for (int j = 0; j < EPT4; ++j) if (val[j]) {
        unsigned key = (unsigned)(e[j] >> 32);
        unsigned g = (key - kmin) >> shft;
        atomicAdd(&ms[g], qval(fdec(key)));
    }
    __syncthreads();

    // hierarchical suffix-inclusive scan over NG groups -> ssA
    {
        const int g0 = tid * (NG / TPB);       // 2 groups per thread
        float ch = ms[g0] + ms[g0 + 1];
        float s = ch;
        const int lane2 = tid & 63;
        #pragma unroll
        for (int o = 1; o < 64; o <<= 1) {
            float t_ = __shfl_down(s, o, 64);
            if (lane2 + o < 64) s += t_;
        }
        if (lane2 == 0) wt[tid >> 6] = s;
        __syncthreads();
        if (tid < 16) {
            float ee = 0.0f;
            for (int w = tid + 1; w < 16; ++w) ee += wt[w];
            we[tid] = ee;
        }
        __syncthreads();
        float gsuf = s + we[tid >> 6];
        float run = gsuf - ch;
        for (int i = 1; i >= 0; --i) { run += ms[g0 + i]; ssA[g0 + i] = run; }
    }
    __syncthreads();

    const float A = sab[row * 8] + sab[row * 8 + 1];
    const float P = rp.P;
    for (int g = tid; g < NG; g += TPB) {
        float SI  = ssA[g];
        float SI1 = (g + 1 < NG) ? ssA[g + 1] : 0.0f;
        if (A + SI > P && A + SI1 <= P) atomicMax(&sh_gstar, g);
    }
    __syncthreads();
    const int gstar = sh_gstar;
    if (tid == 0)
        sh_above = A + ((gstar >= 0 && gstar + 1 < NG) ? ssA[gstar + 1] : 0.0f);

    unsigned long long myb2 = 0ull;
    #pragma unroll
    for (int j = 0; j < EPT4; ++j) if (val[j]) {
        unsigned key = (unsigned)(e[j] >> 32);
        int g = (int)((key - kmin) >> shft);
        int p = tid + j * TPB;
        if (gstar < 0 || g > gstar) {
            unsigned idx = ~(unsigned)(e[j] & 0xFFFFFFFFull);
            unsigned long long k2 = race_key(fdec(key), gurow[p], idx);
            if (k2 > myb2) myb2 = k2;
        } else if (g == gstar) {
            unsigned t = atomicAdd(&sh_tn, 1u);
            if (t < TCAP) { tk[t] = e[j]; tu[t] = __float_as_uint(gurow[p]); }
        }
    }
    __syncthreads();
    unsigned tn = sh_tn; if (tn > TCAP) tn = TCAP;
    if (gstar >= 0 && tn > 0u) {
        int N2 = 64; while (N2 < (int)tn) N2 <<= 1;
        for (int i = tid; i < N2; i += TPB)
            if (i >= (int)tn) { tk[i] = 0ull; tu[i] = 0u; }
        __syncthreads();
        for (int k = 2; k <= N2; k <<= 1) {
            for (int j2 = k >> 1; j2 > 0; j2 >>= 1) {
                for (int i = tid; i < N2; i += TPB) {
                    int ixj = i ^ j2;
                    if (ixj > i) {
                        unsigned long long a = tk[i], b = tk[ixj];
                        if (((i & k) == 0) ? (a < b) : (a > b)) {
                            tk[i] = b; tk[ixj] = a;
                            unsigned ut = tu[i]; tu[i] = tu[ixj]; tu[ixj] = ut;
                        }
                    }
                }
                __syncthreads();
            }
        }
        for (int i = tid; i < N2; i += TPB)
            ssA[i] = (i < (int)tn) ? qval(fdec((unsigned)(tk[i] >> 32))) : 0.0f;
        __syncthreads();
        float* s1 = ssA; float* s2 = ssB;
        for (int d = 1; d < N2; d <<= 1) {
            for (int i = tid; i < N2; i += TPB)
                s2[i] = s1[i] + ((i >= d) ? s1[i - d] : 0.0f);
            __syncthreads();
            float* tm = s1; s1 = s2; s2 = tm;
        }
        const float above = sh_above;
        for (int i = tid; i < (int)tn; i += TPB) {
            float excl = above + ((i == 0) ? 0.0f : s1[i - 1]);
            if (excl <= P) atomicMax(&sh_kst, i + 1);
        }
        __syncthreads();
        const int kst = sh_kst;
        for (int i = tid; i < kst; i += TPB) {
            unsigned idx = ~(unsigned)(tk[i] & 0xFFFFFFFFull);
            unsigned long long k2 =
                race_key(fdec((unsigned)(tk[i] >> 32)), __uint_as_float(tu[i]), idx);
            if (k2 > myb2) myb2 = k2;
        }
        __syncthreads();
    }
    #pragma unroll
    for (int o = 32; o > 0; o >>= 1) {
        unsigned long long other = __shfl_down(myb2, o, 64);
        if (other > myb2) myb2 = other;
    }
    if ((tid & 63) == 0) red_b[tid >> 6] = myb2;
    __syncthreads();
    if (tid == 0) {
        unsigned long long m2 = sh_best;
        #pragma unroll
        for (int w = 0; w < TPB / 64; ++w) if (red_b[w] > m2) m2 = red_b[w];
        out[row] = (int)(~(unsigned)(m2 & 0xFFFFFFFFull));
    }
}

// =================== fallback: proven round-1 single kernel ==================
#define ONT 1024
__global__ __launch_bounds__(ONT, 1)
void sampler_fallback(const float* __restrict__ logits,
                      const float* __restrict__ temps,
                      const float* __restrict__ topps,
                      const float* __restrict__ unoise,
                      int* __restrict__ out)
{
    __shared__ float qmass[NBIN];
    __shared__ float ct[ONT];
    __shared__ float ct2[ONT];
    __shared__ unsigned long long gkeys[GCAP];
    __shared__ float sa[GCAP];
    __shared__ float sb[GCAP];
    __shared__ float wred[16];
    __shared__ unsigned long long sh_cross;
    __shared__ unsigned long long sh_best;
    __shared__ unsigned int gcnt;
    __shared__ int sh_bstar;
    __shared__ float sh_A;
    __shared__ float sh_m;
    __shared__ float sh_Zq;
    __shared__ int sh_kstar;

    const int row = blockIdx.x;
    const int tid = threadIdx.x;
    const float* __restrict__ lrow = logits + (size_t)row * NV;
    const float* __restrict__ urow = unoise + (size_t)row * NV;
    const float invT = 1.0f / temps[row];
    const float topp = topps[row];

    for (int b = tid; b < NBIN; b += ONT) qmass[b] = 0.0f;
    if (tid == 0) { sh_cross = 0ull; sh_best = 0ull; gcnt = 0u; sh_kstar = 0; sh_bstar = 0; sh_A = 0.0f; }
    __syncthreads();

    const float4* __restrict__ l4 = (const float4*)lrow;
    float mloc = -3.402823466e38f;
    const float qscale = 9.5367431640625e-07f;
    for (int v = tid; v < NV4; v += ONT) {
        float4 x = l4[v];
        float xs[4] = {x.x, x.y, x.z, x.w};
        #pragma unroll
        for (int c = 0; c < 4; ++c) {
            float s = xs[c] * invT;
            mloc = fmaxf(mloc, s);
            float q = __expf(s) * qscale;
            float t = fminf(fmaxf(s + 64.0f, 44.0f), 84.0f);
            int bin = (int)((__float_as_uint(t) - BLO) >> BSH);
            bin = min(bin, NBIN - 1);
            atomicAdd(&qmass[bin], q);
        }
    }
    #pragma unroll
    for (int o = 32; o > 0; o >>= 1) mloc = fmaxf(mloc, __shfl_down(mloc, o, 64));
    if ((tid & 63) == 0) wred[tid >> 6] = mloc;
    __syncthreads();
    if (tid < 16) {
        float vv = wred[tid];
        #pragma unroll
        for (int o = 8; o > 0; o >>= 1) vv = fmaxf(vv, __shfl_down(vv, o, 16));
        if (tid == 0) sh_m = vv;
    }
    __syncthreads();
    const float m = sh_m;

    const int b0 = tid * NCH;
    float chs = 0.0f;
    #pragma unroll
    for (int i2 = 0; i2 < NCH; ++i2) {
        int b = b0 + i2;
        if (b < NBIN) chs += qmass[b];
    }
    ct[tid] = chs;
    __syncthreads();
    float* src = ct; float* dst = ct2;
    for (int d = 1; d < ONT; d <<= 1) {
        float val = src[tid] + ((tid + d < ONT) ? src[tid + d] : 0.0f);
        dst[tid] = val;
        __syncthreads();
        float* tm = src; src = dst; dst = tm;
    }
    const float Zq = src[0];
    const float P = topp * Zq;
    {
        float mine = src[tid];
        float nxt = (tid + 1 < ONT) ? src[tid + 1] : 0.0f;
        if (mine > P && nxt <= P)
            atomicMax(&sh_cross, ((unsigned long long)(tid + 1) << 32));
    }
    __syncthreads();
    if (tid == 0) {
        sh_Zq = Zq;
        if (sh_cross == 0ull) { sh_bstar = -1000000; sh_A = 0.0f; }
        else {
            int cstar = (int)(sh_cross >> 32) - 1;
            float run = (cstar + 1 < ONT) ? src[cstar + 1] : 0.0f;
            int bst = -1; float abv = run;
            for (int i2 = NCH - 1; i2 >= 0; --i2) {
                int b = cstar * NCH + i2;
                if (b >= NBIN) continue;
                float inc = qmass[b];
                if (run <= P && run + inc > P) { bst = b; abv = run; break; }
                run += inc;
            }
            if (bst < 0) { bst = cstar * NCH; abv = run; }
            sh_bstar = bst;
            float A = abv;
            if (bst + 1 < NBIN) A -= qmass[bst + 1];
            if (A < 0.0f) A = 0.0f;
            sh_A = A;
        }
    }
    __syncthreads();

    const int bstar = sh_bstar;
    const float Zrow = sh_Zq * 1048576.0f * __expf(-m);
    const float invZrow = 1.0f / Zrow;

    const float4* __restrict__ u4 = (const float4*)urow;
    unsigned long long mybest = 0ull;
    for (int v = tid; v < NV4; v += ONT) {
        float4 x = l4[v];
        float4 uu = u4[v];
        float xs[4] = {x.x, x.y, x.z, x.w};
        float us[4] = {uu.x, uu.y, uu.z, uu.w};
        #pragma unroll
        for (int c = 0; c < 4; ++c) {
            float s = xs[c] * invT;
            float t = fminf(fmaxf(s + 64.0f, 44.0f), 84.0f);
            int bin = (int)((__float_as_uint(t) - BLO) >> BSH);
            bin = min(bin, NBIN - 1);
            if (bin >= bstar + 2) {
                float e = __expf(s - m);
                float noise = fmaxf(-__logf(us[c]), 1e-10f);
                float r = __fdividef(e * invZrow, noise);
                int i = v * 4 + c;
                unsigned long long key = ((unsigned long long)__float_as_uint(r) << 32)
                                       | (unsigned long long)(0xFFFFFFFFu - (unsigned)i);
                if (key > mybest) mybest = key;
            } else if (bin >= bstar - 1) {
                float e = __expf(s - m);
                float p = e / Zrow;
                int i = v * 4 + c;
                unsigned int pos = atomicAdd(&gcnt, 1u);
                if (pos < GCAP)
                    gkeys[pos] = ((unsigned long long)__float_as_uint(p) << 32)
                               | (unsigned long long)(0xFFFFFFFFu - (unsigned)i);
            }
        }
    }
    atomicMax(&sh_best, mybest);
    __syncthreads();

    unsigned int ngu = gcnt; if (ngu > GCAP) ngu = GCAP;
    const int ng = (int)ngu;
    for (int i = tid; i < GCAP; i += ONT) if (i >= ng) gkeys[i] = 0ull;
    __syncthreads();
    if (ng > 0) {
        for (int k = 2; k <= GCAP; k <<= 1) {
            for (int j = k >> 1; j > 0; j >>= 1) {
                for (int i = tid; i < GCAP; i += ONT) {
                    int ixj = i ^ j;
                    if (ixj > i) {
                        unsigned long long a = gkeys[i], b = gkeys[ixj];
                        bool up = ((i & k) == 0);
                        bool sw = up ? (a < b) : (a > b);
                        if (sw) { gkeys[i] = b; gkeys[ixj] = a; }
                    }
                }
                __syncthreads();
            }
        }
        for (int i = tid; i < GCAP; i += ONT)
            sa[i] = __uint_as_float((unsigned)(gkeys[i] >> 32));
        __syncthreads();
        float* ssrc = sa; float* sdst = sb;
        for (int d = 1; d < GCAP; d <<= 1) {
            for (int i = tid; i < GCAP; i += ONT)
                sdst[i] = ssrc[i] + ((i >= d) ? ssrc[i - d] : 0.0f);
            __syncthreads();
            float* tm = ssrc; ssrc = sdst; sdst = tm;
        }
        const float A_p = sh_A / sh_Zq;
        for (int i = tid; i < GCAP; i += ONT) {
            if (i < ng) {
                float excl = (i == 0) ? A_p : (A_p + ssrc[i - 1]);
                if (excl <= topp) atomicMax(&sh_kstar, i + 1);
            }
        }
        __syncthreads();
        const int kst = sh_kstar;
        unsigned long long gb = 0ull;
        for (int i = tid; i < kst; i += ONT) {
            unsigned long long key = gkeys[i];
            unsigned int idx = 0xFFFFFFFFu - (unsigned)(key & 0xFFFFFFFFull);
            float p = __uint_as_float((unsigned)(key >> 32));
            float u = urow[idx];
            float noise = fmaxf(-__logf(u), 1e-10f);
            float r = __fdividef(p, noise);
            unsigned long long k2 = ((unsigned long long)__float_as_uint(r) << 32)
                                  | (unsigned long long)(0xFFFFFFFFu - idx);
            if (k2 > gb) gb = k2;
        }
        atomicMax(&sh_best, gb);
        __syncthreads();
    }
    if (tid == 0) {
        unsigned long long kk = sh_best;
        out[row] = (int)(0xFFFFFFFFu - (unsigned)(kk & 0xFFFFFFFFull));
    }
}

extern "C" void kernel_launch(void* const* d_in, const int* in_sizes, int n_in,
                              void* d_out, int out_size, void* d_ws, size_t ws_size,
                              hipStream_t stream) {
    const float* logits = (const float*)d_in[0];
    const float* temps  = (const float*)d_in[1];
    const float* topps  = (const float*)d_in[2];
    const float* unoise = (const float*)d_in[3];
    int* out = (int*)d_out;

    if (ws_size < WS_NEEDED) {
        hipLaunchKernelGGL(sampler_fallback, dim3(NROW), dim3(ONT), 0, stream,
                           logits, temps, topps, unoise, out);
        return;
    }

    char* ws = (char*)d_ws;
    unsigned* partials = (unsigned*)(ws + WS_PART);
    float* gu   = (float*)(ws + WS_GU);      // overlays partials
    float* zq   = (float*)(ws + WS_ZQ);
    float* sab  = (float*)(ws + WS_SAB);
    unsigned int* gcnt = (unsigned int*)(ws + WS_GCNT);
    unsigned long long* best = (unsigned long long*)(ws + WS_BEST);
    RowParams* params = (RowParams*)(ws + WS_PARAMS);
    unsigned long long* gather = (unsigned long long*)(ws + WS_GATHER);
    unsigned* doneA = (unsigned*)(ws + WS_DONE);
    unsigned* doneB = doneA + NROW;

    hipLaunchKernelGGL(k_init, dim3(1), dim3(512), 0, stream, doneA, doneB);
    hipLaunchKernelGGL(kA, dim3(NROW * 2), dim3(TPB), 0, stream,
                       logits, temps, topps, partials, zq, params, gcnt, best, doneA);
    hipLaunchKernelGGL(kB, dim3(NROW * 2), dim3(TPB), 0, stream,
                       logits, temps, unoise, params, best, gcnt, gather, gu, sab,
                       doneB, out);
}

// Round 9
// 149.488 us; speedup vs baseline: 4.6399x; 4.6399x over previous
//
#include <hip/hip_runtime.h>
#include <stdint.h>

#define NROW 256
#define NV   128000
#define NV4  (NV / 4)
#define HALF_F4 (NV4 / 2)       // 16000 float4 per half-row
#define NBIN 7680
#define NCH  8
#define BLO  0x42300000u        // bits of 44.0f
#define BSH  10
#define GCAP 4096
#define LOG2E 1.44269504088896340736f
#define TPB  1024
#define LCAP 2048
#define RMARG 1.005f
#define T_HI_BITS 0x42A7FFFFu   // ~83.99999 -> bin <= 7679
#define NG   2048               // k4 radix groups
#define TCAP 2048               // k4 tie capacity
#define EPT  (GCAP / TPB)       // 4 elements per thread in k4

// ---- workspace layout (bytes) ----
#define PART_BYTES ((size_t)512 * (NBIN / 2) * 4)        // 7,864,320 (packed u16 pairs)
#define WS_PART   0
#define WS_ZQ     (PART_BYTES)                            // 256*8 f32 (2 slots/row used)
#define WS_SAB    (WS_ZQ   + (size_t)NROW * 8 * 4)
#define WS_GCNT   (WS_SAB  + (size_t)NROW * 8 * 4)
#define WS_BEST   (WS_GCNT + (size_t)NROW * 8 * 4)
#define WS_PARAMS (WS_BEST + (size_t)NROW * 8)
#define WS_GATHER (WS_PARAMS + (size_t)NROW * 16)
#define WS_NEEDED (WS_GATHER + (size_t)NROW * GCAP * 8)   // = 16,283,648
// gu (per-element u_noise for gathered entries) overlays the partials region:
// partials are fully consumed by k2 before k3 writes gu. 256*4096*4 = 4 MB <= 7.86 MB.
#define WS_GU     WS_PART

struct RowParams { int bl; int bh; float P; int pad; };

__device__ __forceinline__ unsigned fenc(float f) {
    unsigned b = __float_as_uint(f);
    return b ^ (((unsigned)((int)b >> 31)) | 0x80000000u);
}
__device__ __forceinline__ float fdec(unsigned e) {
    unsigned m = ((int)e >= 0) ? 0xFFFFFFFFu : 0x80000000u;
    return __uint_as_float(e ^ m);
}

// monotone race key: log2(p/noise) + const = s*log2e - log2(-log2 u) + const
__device__ __forceinline__ unsigned long long race_key(float s, float u, unsigned idx) {
    float nl  = -__builtin_amdgcn_logf(u);
    float l2n = __builtin_amdgcn_logf(nl);
    float keyf = fmaf(s, LOG2E, -l2n);
    return ((unsigned long long)fenc(keyf) << 32) | (unsigned)(~idx);
}

__device__ __forceinline__ int bin_of(float s) {
    float tc = fminf(fmaxf(s + 64.0f, 44.0f), __uint_as_float(T_HI_BITS));
    return (int)((__float_as_uint(tc) - BLO) >> BSH);
}

__device__ __forceinline__ float qval(float s) {       // exp(s) * 2^-20
    return __builtin_amdgcn_exp2f(fmaf(s, LOG2E, -20.0f));
}

__device__ __forceinline__ float cmid(int b) {         // geometric-mid mass of bin b
    float tlo = __uint_as_float(BLO + ((unsigned)b << BSH));
    float thi = __uint_as_float(BLO + ((unsigned)(b + 1) << BSH));
    float tm = 0.5f * (tlo + thi);
    return __builtin_amdgcn_exp2f(fmaf(tm - 64.0f, LOG2E, -20.0f));
}

// ------- K1: integer count histogram + exact Zq reduction + ws init ---------
__global__ __launch_bounds__(TPB)
void k1_hist(const float* __restrict__ logits, const float* __restrict__ temps,
             unsigned* __restrict__ partials, float* __restrict__ zq,
             unsigned int* __restrict__ gcnt, unsigned long long* __restrict__ best)
{
    __shared__ unsigned lh[NBIN];
    __shared__ float wred[16];
    const int row = blockIdx.x >> 1;
    const int sl  = blockIdx.x & 1;
    const int tid = threadIdx.x;
    for (int b = tid; b < NBIN; b += TPB) lh[b] = 0u;
    if (tid == 0 && sl == 0) {              // init for k3 (stream-ordered before it)
        gcnt[row * 8] = 0u;
        best[row] = 0ull;
    }
    __syncthreads();
    const float invT = 1.0f / temps[row];
    const float4* __restrict__ l4 =
        (const float4*)(logits + (size_t)row * NV) + sl * HALF_F4;
    float zacc0 = 0.0f, zacc1 = 0.0f;       // dual accumulators (ILP)
    for (int v = tid; v < HALF_F4; v += TPB) {
        float4 x = l4[v];
        float xs[4] = {x.x, x.y, x.z, x.w};
        #pragma unroll
        for (int c = 0; c < 4; ++c) {
            float s = xs[c] * invT;
            atomicAdd(&lh[bin_of(s)], 1u);
            if (c & 1) zacc1 += qval(s); else zacc0 += qval(s);
        }
    }
    float zacc = zacc0 + zacc1;
    #pragma unroll
    for (int o = 32; o > 0; o >>= 1) zacc += __shfl_down(zacc, o, 64);
    if ((tid & 63) == 0) wred[tid >> 6] = zacc;
    __syncthreads();
    if (tid == 0) {
        float z = 0.0f;
        #pragma unroll
        for (int w = 0; w < TPB / 64; ++w) z += wred[w];
        zq[row * 8 + sl] = z;               // per-slice slot, no atomic, no init
    }
    unsigned* __restrict__ pc = partials + (size_t)blockIdx.x * (NBIN / 2);
    for (int pb = tid; pb < NBIN / 2; pb += TPB)
        pc[pb] = (lh[2 * pb] & 0xFFFFu) | (lh[2 * pb + 1] << 16);
}

// ---------------- K2: merge counts, bounded window [bL', bH] -----------------
__global__ __launch_bounds__(TPB)
void k2_scan(const unsigned* __restrict__ partials, const float* __restrict__ topps,
             const float* __restrict__ zq, RowParams* __restrict__ params)
{
    __shared__ float qm[NBIN];    // mass (then per-bin mass suffix)
    __shared__ float qc[NBIN];    // count (then per-bin count suffix)
    __shared__ float ct[TPB];
    __shared__ float ct2[TPB];
    __shared__ int shbH, shbL, shbLp;
    const int row = blockIdx.x, tid = threadIdx.x;
    const unsigned* __restrict__ p0 = partials + (size_t)(row * 2) * (NBIN / 2);
    const unsigned* __restrict__ p1 = p0 + (NBIN / 2);
    for (int pb = tid; pb < NBIN / 2; pb += TPB) {
        unsigned a = p0[pb], b = p1[pb];
        unsigned c0 = (a & 0xFFFFu) + (b & 0xFFFFu);
        unsigned c1 = (a >> 16) + (b >> 16);
        int b0 = 2 * pb, b1 = 2 * pb + 1;
        qc[b0] = (float)c0; qm[b0] = c0 ? (float)c0 * cmid(b0) : 0.0f;
        qc[b1] = (float)c1; qm[b1] = c1 ? (float)c1 * cmid(b1) : 0.0f;
    }
    if (tid == 0) { shbH = NBIN - 1; shbL = 0; }
    __syncthreads();

    // mass: chunk sums -> suffix scan -> per-bin suffix writeback
    float chs = 0.0f;
    if (tid < NBIN / NCH) {
        int b0 = tid * NCH;
        #pragma unroll
        for (int i = 0; i < NCH; ++i) chs += qm[b0 + i];
    }
    ct[tid] = chs;
    __syncthreads();
    float* src = ct; float* dst = ct2;
    for (int d = 1; d < TPB; d <<= 1) {
        float v = src[tid] + ((tid + d < TPB) ? src[tid + d] : 0.0f);
        dst[tid] = v;
        __syncthreads();
        float* tm = src; src = dst; dst = tm;
    }
    {
        float run = (tid + 1 < TPB) ? src[tid + 1] : 0.0f;
        if (tid < NBIN / NCH) {
            int b0 = tid * NCH;
            for (int i = NCH - 1; i >= 0; --i) { run += qm[b0 + i]; qm[b0 + i] = run; }
        }
    }
    __syncthreads();

    // counts: same machinery
    float chc = 0.0f;
    if (tid < NBIN / NCH) {
        int b0 = tid * NCH;
        #pragma unroll
        for (int i = 0; i < NCH; ++i) chc += qc[b0 + i];
    }
    ct[tid] = chc;
    __syncthreads();
    src = ct; dst = ct2;
    for (int d = 1; d < TPB; d <<= 1) {
        float v = src[tid] + ((tid + d < TPB) ? src[tid + d] : 0.0f);
        dst[tid] = v;
        __syncthreads();
        float* tm = src; src = dst; dst = tm;
    }
    {
        float run = (tid + 1 < TPB) ? src[tid + 1] : 0.0f;
        if (tid < NBIN / NCH) {
            int b0 = tid * NCH;
            for (int i = NCH - 1; i >= 0; --i) { run += qc[b0 + i]; qc[b0 + i] = run; }
        }
    }
    __syncthreads();

    const float P = topps[row] * (zq[row * 8] + zq[row * 8 + 1]);
    if (tid < NBIN / NCH) {
        int b0 = tid * NCH;
        for (int i = 0; i < NCH; ++i) {
            int b = b0 + i;
            float Sb  = qm[b];
            float Sb1 = (b + 1 < NBIN) ? qm[b + 1] : 0.0f;
            if (Sb1 * RMARG <= P) atomicMin(&shbH, b);   // bins > bH definitely kept
            if (Sb > RMARG * P)   atomicMax(&shbL, b);   // bins < bL definitely masked
        }
    }
    __syncthreads();
    const int bH = shbH;
    if (tid == 0) shbLp = bH;
    __syncthreads();
    const float target = (float)GCAP + ((bH + 1 < NBIN) ? qc[bH + 1] : 0.0f);
    const int bL = shbL;
    if (tid < NBIN / NCH) {
        int b0 = tid * NCH;
        for (int i = 0; i < NCH; ++i) {
            int b = b0 + i;
            if (b >= bL && qc[b] <= target) atomicMin(&shbLp, b);  // fit in GCAP
        }
    }
    __syncthreads();
    if (tid == 0) {
        RowParams rp; rp.bl = shbLp; rp.bh = bH; rp.P = P; rp.pad = 0;
        params[row] = rp;
    }
}

// ---------------- K3: race over kept, gather window (+u), exact S_above ------
__global__ __launch_bounds__(TPB)
void k3_race(const float* __restrict__ logits, const float* __restrict__ temps,
             const float* __restrict__ unoise, const RowParams* __restrict__ params,
             unsigned long long* __restrict__ best, unsigned int* __restrict__ gcnt,
             unsigned long long* __restrict__ gather, float* __restrict__ gu,
             float* __restrict__ sab)
{
    __shared__ unsigned long long stage[LCAP];
    __shared__ unsigned stageU[LCAP];
    __shared__ unsigned long long wb[16];
    __shared__ float wsab[16];
    __shared__ unsigned int lcnt;
    __shared__ unsigned int sh_base;
    const int row = blockIdx.x >> 1;
    const int sl  = blockIdx.x & 1;
    const int tid = threadIdx.x;
    if (tid == 0) lcnt = 0u;
    __syncthreads();
    const RowParams rp = params[row];
    const int bl = rp.bl, bh = rp.bh;
    const float invT = 1.0f / temps[row];
    const float4* __restrict__ l4 =
        (const float4*)(logits + (size_t)row * NV) + sl * HALF_F4;
    const float4* __restrict__ u4 =
        (const float4*)(unoise + (size_t)row * NV) + sl * HALF_F4;
    unsigned long long* __restrict__ grow = gather + (size_t)row * GCAP;
    float* __restrict__ gurow = gu + (size_t)row * GCAP;
    unsigned int* __restrict__ gcr = &gcnt[row * 8];
    const int ibase = sl * HALF_F4 * 4;
    unsigned long long mybest = 0ull;
    float sabacc = 0.0f;

    for (int v = tid; v < HALF_F4; v += TPB) {
        float4 x = l4[v];
        float4 uu = u4[v];
        float xs[4] = {x.x, x.y, x.z, x.w};
        float us[4] = {uu.x, uu.y, uu.z, uu.w};
        #pragma unroll
        for (int c = 0; c < 4; ++c) {
            float s = xs[c] * invT;
            int bin = bin_of(s);
            unsigned idx = (unsigned)(ibase + v * 4 + c);
            if (bin > bh) {                       // definitely in nucleus
                unsigned long long key = race_key(s, us[c], idx);
                if (key > mybest) mybest = key;
                sabacc += qval(s);
            } else if (bin >= bl) {               // uncertainty window
                unsigned long long ent =
                    ((unsigned long long)fenc(s) << 32) | (unsigned)(~idx);
                unsigned pos = atomicAdd(&lcnt, 1u);
                if (pos < LCAP) { stage[pos] = ent; stageU[pos] = __float_as_uint(us[c]); }
                else {
                    unsigned gp = atomicAdd(gcr, 1u);
                    if (gp < GCAP) { grow[gp] = ent; gurow[gp] = us[c]; }
                }
            }
        }
    }
    #pragma unroll
    for (int o = 32; o > 0; o >>= 1) {
        unsigned long long other = __shfl_down(mybest, o, 64);
        if (other > mybest) mybest = other;
        sabacc += __shfl_down(sabacc, o, 64);
    }
    if ((tid & 63) == 0) { wb[tid >> 6] = mybest; wsab[tid >> 6] = sabacc; }
    __syncthreads();
    if (tid == 0) {
        unsigned long long m2 = wb[0];
        float sz = wsab[0];
        #pragma unroll
        for (int w = 1; w < TPB / 64; ++w) {
            if (wb[w] > m2) m2 = wb[w];
            sz += wsab[w];
        }
        if (m2) atomicMax(&best[row], m2);
        sab[row * 8 + sl] = sz;               // per-slice slot, no atomic, no init
        unsigned int nn = lcnt; if (nn > LCAP) nn = LCAP;
        sh_base = (nn > 0u) ? atomicAdd(gcr, nn) : 0xFFFFFFF0u;
    }
    __syncthreads();
    unsigned int nn = lcnt; if (nn > LCAP) nn = LCAP;
    unsigned int base = sh_base;
    for (unsigned int i = tid; i < nn; i += TPB) {
        unsigned int p = base + i;
        if (p < GCAP) { grow[p] = stage[i]; gurow[p] = __uint_as_float(stageU[i]); }
    }
}

// -------- K4: radix-select crossing group, tiny tie sort, final winner -------
__global__ __launch_bounds__(TPB)
void k4_select(const RowParams* __restrict__ params,
               const unsigned long long* __restrict__ best,
               const unsigned int* __restrict__ gcnt,
               const unsigned long long* __restrict__ gather,
               const float* __restrict__ gu,
               const float* __restrict__ sab, int* __restrict__ out)
{
    __shared__ float ms[NG];
    __shared__ float ssA[NG];
    __shared__ float ssB[NG];
    __shared__ unsigned long long tk[TCAP];
    __shared__ unsigned tu[TCAP];
    __shared__ unsigned long long red_b[16];
    __shared__ int sh_gstar;
    __shared__ unsigned sh_kmin, sh_kmax, sh_tn;
    __shared__ int sh_kst;
    __shared__ float sh_above;
    __shared__ unsigned long long sh_best;

    const int row = blockIdx.x, tid = threadIdx.x;
    const RowParams rp = params[row];
    unsigned n = gcnt[row * 8]; if (n > GCAP) n = GCAP;
    if (tid == 0) {
        sh_best = best[row]; sh_gstar = -1; sh_tn = 0u; sh_kst = 0;
        sh_kmin = 0xFFFFFFFFu; sh_kmax = 0u;
    }
    for (int g = tid; g < NG; g += TPB) ms[g] = 0.0f;
    __syncthreads();

    const unsigned long long* __restrict__ grow = gather + (size_t)row * GCAP;
    const float* __restrict__ gurow = gu + (size_t)row * GCAP;
    unsigned long long e[EPT];
    bool val[EPT];
    unsigned kmn = 0xFFFFFFFFu, kmx = 0u;
    #pragma unroll
    for (int j = 0; j < EPT; ++j) {
        int p = tid + j * TPB;
        val[j] = (unsigned)p < n;
        e[j] = val[j] ? grow[p] : 0ull;
        if (val[j]) {
            unsigned k = (unsigned)(e[j] >> 32);
            kmn = min(kmn, k); kmx = max(kmx, k);
        }
    }
    atomicMin(&sh_kmin, kmn);
    atomicMax(&sh_kmax, kmx);
    __syncthreads();

    const unsigned kmin = sh_kmin;
    const unsigned span = sh_kmax - kmin;
    const int Lb = 32 - __clz(span);            // span==0 -> 0
    const int shft = (Lb > 11) ? (Lb - 11) : 0; // groups <= 2048
    #pragma unroll
    for (int j = 0; j < EPT; ++j) if (val[j]) {
        unsigned key = (unsigned)(e[j] >> 32);
        unsigned g = (key - kmin) >> shft;
        atomicAdd(&ms[g], qval(fdec(key)));
    }
    __syncthreads();

    // inclusive suffix scan over groups: SI[g] = sum_{g' >= g} ms[g']
    for (int g = tid; g < NG; g += TPB) ssA[g] = ms[g];
    __syncthreads();
    float* src = ssA; float* dst = ssB;
    for (int d = 1; d < NG; d <<= 1) {
        for (int g = tid; g < NG; g += TPB)
            dst[g] = src[g] + ((g + d < NG) ? src[g + d] : 0.0f);
        __syncthreads();
        float* tm = src; src = dst; dst = tm;
    }
    const float A = sab[row * 8] + sab[row * 8 + 1];
    const float P = rp.P;
    for (int g = tid; g < NG; g += TPB) {
        float SI  = src[g];
        float SI1 = (g + 1 < NG) ? src[g + 1] : 0.0f;
        if (A + SI > P && A + SI1 <= P) atomicMax(&sh_gstar, g);
    }
    __syncthreads();
    const int gstar = sh_gstar;
    if (tid == 0)
        sh_above = A + ((gstar >= 0 && gstar + 1 < NG) ? src[gstar + 1] : 0.0f);

    // kept groups race directly; crossing group stages ties
    unsigned long long mybest = 0ull;
    #pragma unroll
    for (int j = 0; j < EPT; ++j) if (val[j]) {
        unsigned key = (unsigned)(e[j] >> 32);
        int g = (int)((key - kmin) >> shft);
        int p = tid + j * TPB;
        if (gstar < 0 || g > gstar) {
            unsigned idx = ~(unsigned)(e[j] & 0xFFFFFFFFull);
            unsigned long long k2 = race_key(fdec(key), gurow[p], idx);
            if (k2 > mybest) mybest = k2;
        } else if (g == gstar) {
            unsigned t = atomicAdd(&sh_tn, 1u);
            if (t < TCAP) { tk[t] = e[j]; tu[t] = __float_as_uint(gurow[p]); }
        }
    }
    __syncthreads();
    unsigned tn = sh_tn; if (tn > TCAP) tn = TCAP;
    if (gstar >= 0 && tn > 0u) {
        int N2 = 64; while (N2 < (int)tn) N2 <<= 1;
        for (int i = tid; i < N2; i += TPB)
            if (i >= (int)tn) { tk[i] = 0ull; tu[i] = 0u; }
        __syncthreads();
        // bitonic sort descending on (key, ~idx), payload tu
        for (int k = 2; k <= N2; k <<= 1) {
            for (int j2 = k >> 1; j2 > 0; j2 >>= 1) {
                for (int i = tid; i < N2; i += TPB) {
                    int ixj = i ^ j2;
                    if (ixj > i) {
                        unsigned long long a = tk[i], b = tk[ixj];
                        if (((i & k) == 0) ? (a < b) : (a > b)) {
                            tk[i] = b; tk[ixj] = a;
                            unsigned ut = tu[i]; tu[i] = tu[ixj]; tu[ixj] = ut;
                        }
                    }
                }
                __syncthreads();
            }
        }
        // inclusive prefix scan of tie masses
        for (int i = tid; i < N2; i += TPB)
            ssA[i] = (i < (int)tn) ? qval(fdec((unsigned)(tk[i] >> 32))) : 0.0f;
        __syncthreads();
        float* s1 = ssA; float* s2 = ssB;
        for (int d = 1; d < N2; d <<= 1) {
            for (int i = tid; i < N2; i += TPB)
                s2[i] = s1[i] + ((i >= d) ? s1[i - d] : 0.0f);
            __syncthreads();
            float* tm = s1; s1 = s2; s2 = tm;
        }
        const float above = sh_above;
        for (int i = tid; i < (int)tn; i += TPB) {
            float excl = above + ((i == 0) ? 0.0f : s1[i - 1]);
            if (excl <= P) atomicMax(&sh_kst, i + 1);
        }
        __syncthreads();
        const int kst = sh_kst;
        for (int i = tid; i < kst; i += TPB) {
            unsigned idx = ~(unsigned)(tk[i] & 0xFFFFFFFFull);
            unsigned long long k2 =
                race_key(fdec((unsigned)(tk[i] >> 32)), __uint_as_float(tu[i]), idx);
            if (k2 > mybest) mybest = k2;
        }
        __syncthreads();
    }
    #pragma unroll
    for (int o = 32; o > 0; o >>= 1) {
        unsigned long long other = __shfl_down(mybest, o, 64);
        if (other > mybest) mybest = other;
    }
    if ((tid & 63) == 0) red_b[tid >> 6] = mybest;
    __syncthreads();
    if (tid == 0) {
        unsigned long long m2 = sh_best;
        #pragma unroll
        for (int w = 0; w < TPB / 64; ++w) if (red_b[w] > m2) m2 = red_b[w];
        out[row] = (int)(~(unsigned)(m2 & 0xFFFFFFFFull));
    }
}

// =================== fallback: proven round-1 single kernel ==================
#define ONT 1024
__global__ __launch_bounds__(ONT, 1)
void sampler_fallback(const float* __restrict__ logits,
                      const float* __restrict__ temps,
                      const float* __restrict__ topps,
                      const float* __restrict__ unoise,
                      int* __restrict__ out)
{
    __shared__ float qmass[NBIN];
    __shared__ float ct[ONT];
    __shared__ float ct2[ONT];
    __shared__ unsigned long long gkeys[GCAP];
    __shared__ float sa[GCAP];
    __shared__ float sb[GCAP];
    __shared__ float wred[16];
    __shared__ unsigned long long sh_cross;
    __shared__ unsigned long long sh_best;
    __shared__ unsigned int gcnt;
    __shared__ int sh_bstar;
    __shared__ float sh_A;
    __shared__ float sh_m;
    __shared__ float sh_Zq;
    __shared__ int sh_kstar;

    const int row = blockIdx.x;
    const int tid = threadIdx.x;
    const float* __restrict__ lrow = logits + (size_t)row * NV;
    const float* __restrict__ urow = unoise + (size_t)row * NV;
    const float invT = 1.0f / temps[row];
    const float topp = topps[row];

    for (int b = tid; b < NBIN; b += ONT) qmass[b] = 0.0f;
    if (tid == 0) { sh_cross = 0ull; sh_best = 0ull; gcnt = 0u; sh_kstar = 0; sh_bstar = 0; sh_A = 0.0f; }
    __syncthreads();

    const float4* __restrict__ l4 = (const float4*)lrow;
    float mloc = -3.402823466e38f;
    const float qscale = 9.5367431640625e-07f;
    for (int v = tid; v < NV4; v += ONT) {
        float4 x = l4[v];
        float xs[4] = {x.x, x.y, x.z, x.w};
        #pragma unroll
        for (int c = 0; c < 4; ++c) {
            float s = xs[c] * invT;
            mloc = fmaxf(mloc, s);
            float q = __expf(s) * qscale;
            float t = fminf(fmaxf(s + 64.0f, 44.0f), 84.0f);
            int bin = (int)((__float_as_uint(t) - BLO) >> BSH);
            bin = min(bin, NBIN - 1);
            atomicAdd(&qmass[bin], q);
        }
    }
    #pragma unroll
    for (int o = 32; o > 0; o >>= 1) mloc = fmaxf(mloc, __shfl_down(mloc, o, 64));
    if ((tid & 63) == 0) wred[tid >> 6] = mloc;
    __syncthreads();
    if (tid < 16) {
        float vv = wred[tid];
        #pragma unroll
        for (int o = 8; o > 0; o >>= 1) vv = fmaxf(vv, __shfl_down(vv, o, 16));
        if (tid == 0) sh_m = vv;
    }
    __syncthreads();
    const float m = sh_m;

    const int b0 = tid * NCH;
    float chs = 0.0f;
    #pragma unroll
    for (int i2 = 0; i2 < NCH; ++i2) {
        int b = b0 + i2;
        if (b < NBIN) chs += qmass[b];
    }
    ct[tid] = chs;
    __syncthreads();
    float* src = ct; float* dst = ct2;
    for (int d = 1; d < ONT; d <<= 1) {
        float val = src[tid] + ((tid + d < ONT) ? src[tid + d] : 0.0f);
        dst[tid] = val;
        __syncthreads();
        float* tm = src; src = dst; dst = tm;
    }
    const float Zq = src[0];
    const float P = topp * Zq;
    {
        float mine = src[tid];
        float nxt = (tid + 1 < ONT) ? src[tid + 1] : 0.0f;
        if (mine > P && nxt <= P)
            atomicMax(&sh_cross, ((unsigned long long)(tid + 1) << 32));
    }
    __syncthreads();
    if (tid == 0) {
        sh_Zq = Zq;
        if (sh_cross == 0ull) { sh_bstar = -1000000; sh_A = 0.0f; }
        else {
            int cstar = (int)(sh_cross >> 32) - 1;
            float run = (cstar + 1 < ONT) ? src[cstar + 1] : 0.0f;
            int bst = -1; float abv = run;
            for (int i2 = NCH - 1; i2 >= 0; --i2) {
                int b = cstar * NCH + i2;
                if (b >= NBIN) continue;
                float inc = qmass[b];
                if (run <= P && run + inc > P) { bst = b; abv = run; break; }
                run += inc;
            }
            if (bst < 0) { bst = cstar * NCH; abv = run; }
            sh_bstar = bst;
            float A = abv;
            if (bst + 1 < NBIN) A -= qmass[bst + 1];
            if (A < 0.0f) A = 0.0f;
            sh_A = A;
        }
    }
    __syncthreads();

    const int bstar = sh_bstar;
    const float Zrow = sh_Zq * 1048576.0f * __expf(-m);
    const float invZrow = 1.0f / Zrow;

    const float4* __restrict__ u4 = (const float4*)urow;
    unsigned long long mybest = 0ull;
    for (int v = tid; v < NV4; v += ONT) {
        float4 x = l4[v];
        float4 uu = u4[v];
        float xs[4] = {x.x, x.y, x.z, x.w};
        float us[4] = {uu.x, uu.y, uu.z, uu.w};
        #pragma unroll
        for (int c = 0; c < 4; ++c) {
            float s = xs[c] * invT;
            float t = fminf(fmaxf(s + 64.0f, 44.0f), 84.0f);
            int bin = (int)((__float_as_uint(t) - BLO) >> BSH);
            bin = min(bin, NBIN - 1);
            if (bin >= bstar + 2) {
                float e = __expf(s - m);
                float noise = fmaxf(-__logf(us[c]), 1e-10f);
                float r = __fdividef(e * invZrow, noise);
                int i = v * 4 + c;
                unsigned long long key = ((unsigned long long)__float_as_uint(r) << 32)
                                       | (unsigned long long)(0xFFFFFFFFu - (unsigned)i);
                if (key > mybest) mybest = key;
            } else if (bin >= bstar - 1) {
                float e = __expf(s - m);
                float p = e / Zrow;
                int i = v * 4 + c;
                unsigned int pos = atomicAdd(&gcnt, 1u);
                if (pos < GCAP)
                    gkeys[pos] = ((unsigned long long)__float_as_uint(p) << 32)
                               | (unsigned long long)(0xFFFFFFFFu - (unsigned)i);
            }
        }
    }
    atomicMax(&sh_best, mybest);
    __syncthreads();

    unsigned int ngu = gcnt; if (ngu > GCAP) ngu = GCAP;
    const int ng = (int)ngu;
    for (int i = tid; i < GCAP; i += ONT) if (i >= ng) gkeys[i] = 0ull;
    __syncthreads();
    if (ng > 0) {
        for (int k = 2; k <= GCAP; k <<= 1) {
            for (int j = k >> 1; j > 0; j >>= 1) {
                for (int i = tid; i < GCAP; i += ONT) {
                    int ixj = i ^ j;
                    if (ixj > i) {
                        unsigned long long a = gkeys[i], b = gkeys[ixj];
                        bool up = ((i & k) == 0);
                        bool sw = up ? (a < b) : (a > b);
                        if (sw) { gkeys[i] = b; gkeys[ixj] = a; }
                    }
                }
                __syncthreads();
            }
        }
        for (int i = tid; i < GCAP; i += ONT)
            sa[i] = __uint_as_float((unsigned)(gkeys[i] >> 32));
        __syncthreads();
        float* ssrc = sa; float* sdst = sb;
        for (int d = 1; d < GCAP; d <<= 1) {
            for (int i = tid; i < GCAP; i += ONT)
                sdst[i] = ssrc[i] + ((i >= d) ? ssrc[i - d] : 0.0f);
            __syncthreads();
            float* tm = ssrc; ssrc = sdst; sdst = tm;
        }
        const float A_p = sh_A / sh_Zq;
        for (int i = tid; i < GCAP; i += ONT) {
            if (i < ng) {
                float excl = (i == 0) ? A_p : (A_p + ssrc[i - 1]);
                if (excl <= topp) atomicMax(&sh_kstar, i + 1);
            }
        }
        __syncthreads();
        const int kst = sh_kstar;
        unsigned long long gb = 0ull;
        for (int i = tid; i < kst; i += ONT) {
            unsigned long long key = gkeys[i];
            unsigned int idx = 0xFFFFFFFFu - (unsigned)(key & 0xFFFFFFFFull);
            float p = __uint_as_float((unsigned)(key >> 32));
            float u = urow[idx];
            float noise = fmaxf(-__logf(u), 1e-10f);
            float r = __fdividef(p, noise);
            unsigned long long k2 = ((unsigned long long)__float_as_uint(r) << 32)
                                  | (unsigned long long)(0xFFFFFFFFu - idx);
            if (k2 > gb) gb = k2;
        }
        atomicMax(&sh_best, gb);
        __syncthreads();
    }
    if (tid == 0) {
        unsigned long long kk = sh_best;
        out[row] = (int)(0xFFFFFFFFu - (unsigned)(kk & 0xFFFFFFFFull));
    }
}

extern "C" void kernel_launch(void* const* d_in, const int* in_sizes, int n_in,
                              void* d_out, int out_size, void* d_ws, size_t ws_size,
                              hipStream_t stream) {
    const float* logits = (const float*)d_in[0];
    const float* temps  = (const float*)d_in[1];
    const float* topps  = (const float*)d_in[2];
    const float* unoise = (const float*)d_in[3];
    int* out = (int*)d_out;

    if (ws_size < WS_NEEDED) {
        hipLaunchKernelGGL(sampler_fallback, dim3(NROW), dim3(ONT), 0, stream,
                           logits, temps, topps, unoise, out);
        return;
    }

    char* ws = (char*)d_ws;
    unsigned* partials = (unsigned*)(ws + WS_PART);
    float* gu   = (float*)(ws + WS_GU);      // overlays partials (consumed by k2)
    float* zq   = (float*)(ws + WS_ZQ);
    float* sab  = (float*)(ws + WS_SAB);
    unsigned int* gcnt = (unsigned int*)(ws + WS_GCNT);
    unsigned long long* best = (unsigned long long*)(ws + WS_BEST);
    RowParams* params = (RowParams*)(ws + WS_PARAMS);
    unsigned long long* gather = (unsigned long long*)(ws + WS_GATHER);

    hipLaunchKernelGGL(k1_hist, dim3(NROW * 2), dim3(TPB), 0, stream,
                       logits, temps, partials, zq, gcnt, best);
    hipLaunchKernelGGL(k2_scan, dim3(NROW), dim3(TPB), 0, stream,
                       partials, topps, zq, params);
    hipLaunchKernelGGL(k3_race, dim3(NROW * 2), dim3(TPB), 0, stream,
                       logits, temps, unoise, params, best, gcnt, gather, gu, sab);
    hipLaunchKernelGGL(k4_select, dim3(NROW), dim3(TPB), 0, stream,
                       params, best, gcnt, gather, gu, sab, out);
}

// Round 10
// 141.457 us; speedup vs baseline: 4.9034x; 1.0568x over previous
//
#include <hip/hip_runtime.h>
#include <stdint.h>

#define NROW 256
#define NV   128000
#define NV4  (NV / 4)
#define NBIN 7680
#define NCH  8
#define BLO  0x42300000u        // bits of 44.0f
#define BSH  10
#define GCAP 4096
#define LOG2E 1.44269504088896340736f
#define TPB  1024
#define RMARG 1.005f
#define T_HI_BITS 0x42A7FFFFu   // ~83.99999 -> bin <= 7679
#define NG   2048               // select radix groups
#define TCAP 2048               // tie capacity

#define WS_NEEDED ((size_t)NROW * 16)

struct RowParams { int bl; int bh; float P; int pad; };

__device__ __forceinline__ unsigned fenc(float f) {
    unsigned b = __float_as_uint(f);
    return b ^ (((unsigned)((int)b >> 31)) | 0x80000000u);
}
__device__ __forceinline__ float fdec(unsigned e) {
    unsigned m = ((int)e >= 0) ? 0xFFFFFFFFu : 0x80000000u;
    return __uint_as_float(e ^ m);
}

// monotone race key: log2(p/noise) + const = s*log2e - log2(-log2 u) + const
__device__ __forceinline__ unsigned long long race_key(float s, float u, unsigned idx) {
    float nl  = -__builtin_amdgcn_logf(u);
    float l2n = __builtin_amdgcn_logf(nl);
    float keyf = fmaf(s, LOG2E, -l2n);
    return ((unsigned long long)fenc(keyf) << 32) | (unsigned)(~idx);
}

__device__ __forceinline__ int bin_of(float s) {
    float tc = fminf(fmaxf(s + 64.0f, 44.0f), __uint_as_float(T_HI_BITS));
    return (int)((__float_as_uint(tc) - BLO) >> BSH);
}

__device__ __forceinline__ float qval(float s) {       // exp(s) * 2^-20
    return __builtin_amdgcn_exp2f(fmaf(s, LOG2E, -20.0f));
}

__device__ __forceinline__ float cmid(int b) {         // geometric-mid mass of bin b
    float tlo = __uint_as_float(BLO + ((unsigned)b << BSH));
    float thi = __uint_as_float(BLO + ((unsigned)(b + 1) << BSH));
    float tm = 0.5f * (tlo + thi);
    return __builtin_amdgcn_exp2f(fmaf(tm - 64.0f, LOG2E, -20.0f));
}

// ===== Kernel A: one block per row — histogram + exact Zq + window scan =====
__global__ __launch_bounds__(TPB, 4)
void kA_hist_scan(const float* __restrict__ logits, const float* __restrict__ temps,
                  const float* __restrict__ topps, RowParams* __restrict__ params)
{
    __shared__ unsigned lh[NBIN];      // 30 KB counts
    __shared__ float qm[NBIN];         // 30 KB mass suffix
    __shared__ float qc[NBIN];         // 30 KB count suffix
    __shared__ float ct[TPB];
    __shared__ float ct2[TPB];
    __shared__ float wred[16];
    __shared__ float shZq;
    __shared__ int shbH, shbL, shbLp;

    const int row = blockIdx.x;
    const int tid = threadIdx.x;
    for (int b = tid; b < NBIN; b += TPB) lh[b] = 0u;
    if (tid == 0) { shbH = NBIN - 1; shbL = 0; }
    __syncthreads();

    const float invT = 1.0f / temps[row];
    const float4* __restrict__ l4 = (const float4*)(logits + (size_t)row * NV);
    float zacc = 0.0f;
    for (int v = tid; v < NV4; v += 2 * TPB) {
        int v1 = v + TPB;
        bool g1 = v1 < NV4;
        float4 x0 = l4[v];
        float4 x1 = l4[g1 ? v1 : v];
        float xs0[4] = {x0.x, x0.y, x0.z, x0.w};
        float xs1[4] = {x1.x, x1.y, x1.z, x1.w};
        #pragma unroll
        for (int c = 0; c < 4; ++c) {
            float s = xs0[c] * invT;
            atomicAdd(&lh[bin_of(s)], 1u);
            zacc += qval(s);
        }
        #pragma unroll
        for (int c = 0; c < 4; ++c) {
            if (g1) {
                float s = xs1[c] * invT;
                atomicAdd(&lh[bin_of(s)], 1u);
                zacc += qval(s);
            }
        }
    }
    #pragma unroll
    for (int o = 32; o > 0; o >>= 1) zacc += __shfl_down(zacc, o, 64);
    if ((tid & 63) == 0) wred[tid >> 6] = zacc;
    __syncthreads();
    if (tid == 0) {
        float z = 0.0f;
        #pragma unroll
        for (int w = 0; w < TPB / 64; ++w) z += wred[w];
        shZq = z;
    }
    __syncthreads();

    // counts -> (mass, count) arrays
    for (int b = tid; b < NBIN; b += TPB) {
        unsigned c = lh[b];
        qc[b] = (float)c;
        qm[b] = c ? (float)c * cmid(b) : 0.0f;
    }
    __syncthreads();

    // mass: chunk sums -> suffix scan -> per-bin suffix writeback
    float chs = 0.0f;
    if (tid < NBIN / NCH) {
        int b0 = tid * NCH;
        #pragma unroll
        for (int i = 0; i < NCH; ++i) chs += qm[b0 + i];
    }
    ct[tid] = chs;
    __syncthreads();
    float* src = ct; float* dst = ct2;
    for (int d = 1; d < TPB; d <<= 1) {
        float v = src[tid] + ((tid + d < TPB) ? src[tid + d] : 0.0f);
        dst[tid] = v;
        __syncthreads();
        float* tm = src; src = dst; dst = tm;
    }
    {
        float run = (tid + 1 < TPB) ? src[tid + 1] : 0.0f;
        if (tid < NBIN / NCH) {
            int b0 = tid * NCH;
            for (int i = NCH - 1; i >= 0; --i) { run += qm[b0 + i]; qm[b0 + i] = run; }
        }
    }
    __syncthreads();

    // counts: same machinery
    float chc = 0.0f;
    if (tid < NBIN / NCH) {
        int b0 = tid * NCH;
        #pragma unroll
        for (int i = 0; i < NCH; ++i) chc += qc[b0 + i];
    }
    ct[tid] = chc;
    __syncthreads();
    src = ct; dst = ct2;
    for (int d = 1; d < TPB; d <<= 1) {
        float v = src[tid] + ((tid + d < TPB) ? src[tid + d] : 0.0f);
        dst[tid] = v;
        __syncthreads();
        float* tm = src; src = dst; dst = tm;
    }
    {
        float run = (tid + 1 < TPB) ? src[tid + 1] : 0.0f;
        if (tid < NBIN / NCH) {
            int b0 = tid * NCH;
            for (int i = NCH - 1; i >= 0; --i) { run += qc[b0 + i]; qc[b0 + i] = run; }
        }
    }
    __syncthreads();

    const float P = topps[row] * shZq;
    if (tid < NBIN / NCH) {
        int b0 = tid * NCH;
        for (int i = 0; i < NCH; ++i) {
            int b = b0 + i;
            float Sb  = qm[b];
            float Sb1 = (b + 1 < NBIN) ? qm[b + 1] : 0.0f;
            if (Sb1 * RMARG <= P) atomicMin(&shbH, b);   // bins > bH definitely kept
            if (Sb > RMARG * P)   atomicMax(&shbL, b);   // bins < bL definitely masked
        }
    }
    __syncthreads();
    const int bH = shbH;
    if (tid == 0) shbLp = bH;
    __syncthreads();
    const float target = (float)GCAP + ((bH + 1 < NBIN) ? qc[bH + 1] : 0.0f);
    const int bL = shbL;
    if (tid < NBIN / NCH) {
        int b0 = tid * NCH;
        for (int i = 0; i < NCH; ++i) {
            int b = b0 + i;
            if (b >= bL && qc[b] <= target) atomicMin(&shbLp, b);  // window fits GCAP
        }
    }
    __syncthreads();
    if (tid == 0) {
        RowParams rp; rp.bl = shbLp; rp.bh = bH; rp.P = P; rp.pad = 0;
        params[row] = rp;
    }
}

// ===== Kernel B: one block per row — race + LDS-staged window + select ======
__global__ __launch_bounds__(TPB, 4)
void kB_race_select(const float* __restrict__ logits, const float* __restrict__ temps,
                    const float* __restrict__ unoise,
                    const RowParams* __restrict__ params, int* __restrict__ out)
{
    __shared__ unsigned long long stage[GCAP];   // 32 KB window keys
    __shared__ unsigned stageU[GCAP];            // 16 KB window u
    __shared__ float ms[NG];                     //  8 KB group masses
    __shared__ float ssA[NG];                    //  8 KB scan ping
    __shared__ float ssB[NG];                    //  8 KB scan pong
    __shared__ unsigned long long tk[TCAP];      // 16 KB tie keys
    __shared__ unsigned tu[TCAP];                //  8 KB tie u
    __shared__ float wsab[16];
    __shared__ unsigned long long red_b[16];
    __shared__ unsigned lcnt;
    __shared__ float shA;
    __shared__ int sh_gstar, sh_kst;
    __shared__ unsigned sh_kmin, sh_kmax, sh_tn;
    __shared__ float sh_above;

    const int row = blockIdx.x;
    const int tid = threadIdx.x;
    if (tid == 0) {
        lcnt = 0u; sh_gstar = -1; sh_tn = 0u; sh_kst = 0;
        sh_kmin = 0xFFFFFFFFu; sh_kmax = 0u;
    }
    __syncthreads();

    const RowParams rp = params[row];
    const int bl = rp.bl, bh = rp.bh;
    const float P = rp.P;
    const float invT = 1.0f / temps[row];
    const float4* __restrict__ l4 = (const float4*)(logits + (size_t)row * NV);
    const float4* __restrict__ u4 = (const float4*)(unoise + (size_t)row * NV);
    unsigned long long mybest = 0ull;
    float sabacc = 0.0f;

    for (int v = tid; v < NV4; v += 2 * TPB) {
        int v1 = v + TPB;
        bool g1 = v1 < NV4;
        float4 x0 = l4[v];
        float4 u0 = u4[v];
        float4 x1 = l4[g1 ? v1 : v];
        float4 u1 = u4[g1 ? v1 : v];
        float xs0[4] = {x0.x, x0.y, x0.z, x0.w};
        float us0[4] = {u0.x, u0.y, u0.z, u0.w};
        float xs1[4] = {x1.x, x1.y, x1.z, x1.w};
        float us1[4] = {u1.x, u1.y, u1.z, u1.w};
        #pragma unroll
        for (int c = 0; c < 4; ++c) {
            float s = xs0[c] * invT;
            int bin = bin_of(s);
            unsigned idx = (unsigned)(v * 4 + c);
            if (bin > bh) {
                unsigned long long key = race_key(s, us0[c], idx);
                if (key > mybest) mybest = key;
                sabacc += qval(s);
            } else if (bin >= bl) {
                unsigned pos = atomicAdd(&lcnt, 1u);
                if (pos < GCAP) {
                    stage[pos] = ((unsigned long long)fenc(s) << 32) | (unsigned)(~idx);
                    stageU[pos] = __float_as_uint(us0[c]);
                }
            }
        }
        #pragma unroll
        for (int c = 0; c < 4; ++c) {
            if (g1) {
                float s = xs1[c] * invT;
                int bin = bin_of(s);
                unsigned idx = (unsigned)(v1 * 4 + c);
                if (bin > bh) {
                    unsigned long long key = race_key(s, us1[c], idx);
                    if (key > mybest) mybest = key;
                    sabacc += qval(s);
                } else if (bin >= bl) {
                    unsigned pos = atomicAdd(&lcnt, 1u);
                    if (pos < GCAP) {
                        stage[pos] = ((unsigned long long)fenc(s) << 32) | (unsigned)(~idx);
                        stageU[pos] = __float_as_uint(us1[c]);
                    }
                }
            }
        }
    }

    // reduce S_above (exact kept mass); mybest stays in-register through select
    #pragma unroll
    for (int o = 32; o > 0; o >>= 1) sabacc += __shfl_down(sabacc, o, 64);
    if ((tid & 63) == 0) wsab[tid >> 6] = sabacc;
    __syncthreads();
    if (tid == 0) {
        float sz = 0.0f;
        #pragma unroll
        for (int w = 0; w < TPB / 64; ++w) sz += wsab[w];
        shA = sz;
    }
    for (int g = tid; g < NG; g += TPB) ms[g] = 0.0f;
    __syncthreads();

    unsigned n = lcnt; if (n > GCAP) n = GCAP;
    if (n > 0) {
        // pass 1: key min/max
        unsigned kmn = 0xFFFFFFFFu, kmx = 0u;
        for (unsigned p = tid; p < n; p += TPB) {
            unsigned k = (unsigned)(stage[p] >> 32);
            kmn = min(kmn, k); kmx = max(kmx, k);
        }
        atomicMin(&sh_kmin, kmn);
        atomicMax(&sh_kmax, kmx);
        __syncthreads();
        const unsigned kmin = sh_kmin;
        const unsigned span = sh_kmax - kmin;
        const int Lb = 32 - __clz(span);            // span==0 -> 0
        const int shft = (Lb > 11) ? (Lb - 11) : 0; // groups <= 2048

        // pass 2: group mass histogram
        for (unsigned p = tid; p < n; p += TPB) {
            unsigned key = (unsigned)(stage[p] >> 32);
            atomicAdd(&ms[(key - kmin) >> shft], qval(fdec(key)));
        }
        __syncthreads();

        // suffix-inclusive scan over groups
        for (int g = tid; g < NG; g += TPB) ssA[g] = ms[g];
        __syncthreads();
        float* src = ssA; float* dst = ssB;
        for (int d = 1; d < NG; d <<= 1) {
            for (int g = tid; g < NG; g += TPB)
                dst[g] = src[g] + ((g + d < NG) ? src[g + d] : 0.0f);
            __syncthreads();
            float* tm = src; src = dst; dst = tm;
        }
        const float A = shA;
        for (int g = tid; g < NG; g += TPB) {
            float SI  = src[g];
            float SI1 = (g + 1 < NG) ? src[g + 1] : 0.0f;
            if (A + SI > P && A + SI1 <= P) atomicMax(&sh_gstar, g);
        }
        __syncthreads();
        const int gstar = sh_gstar;
        if (tid == 0)
            sh_above = A + ((gstar >= 0 && gstar + 1 < NG) ? src[gstar + 1] : 0.0f);

        // pass 3: kept groups race; crossing group stages ties
        for (unsigned p = tid; p < n; p += TPB) {
            unsigned long long e = stage[p];
            unsigned key = (unsigned)(e >> 32);
            int g = (int)((key - kmin) >> shft);
            if (gstar < 0 || g > gstar) {
                unsigned idx = ~(unsigned)(e & 0xFFFFFFFFull);
                unsigned long long k2 =
                    race_key(fdec(key), __uint_as_float(stageU[p]), idx);
                if (k2 > mybest) mybest = k2;
            } else if (g == gstar) {
                unsigned t = atomicAdd(&sh_tn, 1u);
                if (t < TCAP) { tk[t] = e; tu[t] = stageU[p]; }
            }
        }
        __syncthreads();
        unsigned tn = sh_tn; if (tn > TCAP) tn = TCAP;
        if (gstar >= 0 && tn > 0u) {
            int N2 = 64; while (N2 < (int)tn) N2 <<= 1;
            for (int i = tid; i < N2; i += TPB)
                if (i >= (int)tn) { tk[i] = 0ull; tu[i] = 0u; }
            __syncthreads();
            // bitonic sort descending on (key, ~idx), payload tu
            for (int k = 2; k <= N2; k <<= 1) {
                for (int j2 = k >> 1; j2 > 0; j2 >>= 1) {
                    for (int i = tid; i < N2; i += TPB) {
                        int ixj = i ^ j2;
                        if (ixj > i) {
                            unsigned long long a = tk[i], b = tk[ixj];
                            if (((i & k) == 0) ? (a < b) : (a > b)) {
                                tk[i] = b; tk[ixj] = a;
                                unsigned ut = tu[i]; tu[i] = tu[ixj]; tu[ixj] = ut;
                            }
                        }
                    }
                    __syncthreads();
                }
            }
            // inclusive prefix scan of tie masses
            for (int i = tid; i < N2; i += TPB)
                ssA[i] = (i < (int)tn) ? qval(fdec((unsigned)(tk[i] >> 32))) : 0.0f;
            __syncthreads();
            float* s1 = ssA; float* s2 = ssB;
            for (int d = 1; d < N2; d <<= 1) {
                for (int i = tid; i < N2; i += TPB)
                    s2[i] = s1[i] + ((i >= d) ? s1[i - d] : 0.0f);
                __syncthreads();
                float* tm = s1; s1 = s2; s2 = tm;
            }
            const float above = sh_above;
            for (int i = tid; i < (int)tn; i += TPB) {
                float excl = above + ((i == 0) ? 0.0f : s1[i - 1]);
                if (excl <= P) atomicMax(&sh_kst, i + 1);
            }
            __syncthreads();
            const int kst = sh_kst;
            for (int i = tid; i < kst; i += TPB) {
                unsigned idx = ~(unsigned)(tk[i] & 0xFFFFFFFFull);
                unsigned long long k2 =
                    race_key(fdec((unsigned)(tk[i] >> 32)), __uint_as_float(tu[i]), idx);
                if (k2 > mybest) mybest = k2;
            }
            __syncthreads();
        }
    }

    // final winner reduce
    #pragma unroll
    for (int o = 32; o > 0; o >>= 1) {
        unsigned long long other = __shfl_down(mybest, o, 64);
        if (other > mybest) mybest = other;
    }
    if ((tid & 63) == 0) red_b[tid >> 6] = mybest;
    __syncthreads();
    if (tid == 0) {
        unsigned long long m2 = red_b[0];
        #pragma unroll
        for (int w = 1; w < TPB / 64; ++w) if (red_b[w] > m2) m2 = red_b[w];
        out[row] = (int)(~(unsigned)(m2 & 0xFFFFFFFFull));
    }
}

// =================== fallback: proven round-1 single kernel ==================
#define ONT 1024
__global__ __launch_bounds__(ONT, 1)
void sampler_fallback(const float* __restrict__ logits,
                      const float* __restrict__ temps,
                      const float* __restrict__ topps,
                      const float* __restrict__ unoise,
                      int* __restrict__ out)
{
    __shared__ float qmass[NBIN];
    __shared__ float ct[ONT];
    __shared__ float ct2[ONT];
    __shared__ unsigned long long gkeys[GCAP];
    __shared__ float sa[GCAP];
    __shared__ float sb[GCAP];
    __shared__ float wred[16];
    __shared__ unsigned long long sh_cross;
    __shared__ unsigned long long sh_best;
    __shared__ unsigned int gcnt;
    __shared__ int sh_bstar;
    __shared__ float sh_A;
    __shared__ float sh_m;
    __shared__ float sh_Zq;
    __shared__ int sh_kstar;

    const int row = blockIdx.x;
    const int tid = threadIdx.x;
    const float* __restrict__ lrow = logits + (size_t)row * NV;
    const float* __restrict__ urow = unoise + (size_t)row * NV;
    const float invT = 1.0f / temps[row];
    const float topp = topps[row];

    for (int b = tid; b < NBIN; b += ONT) qmass[b] = 0.0f;
    if (tid == 0) { sh_cross = 0ull; sh_best = 0ull; gcnt = 0u; sh_kstar = 0; sh_bstar = 0; sh_A = 0.0f; }
    __syncthreads();

    const float4* __restrict__ l4 = (const float4*)lrow;
    float mloc = -3.402823466e38f;
    const float qscale = 9.5367431640625e-07f;
    for (int v = tid; v < NV4; v += ONT) {
        float4 x = l4[v];
        float xs[4] = {x.x, x.y, x.z, x.w};
        #pragma unroll
        for (int c = 0; c < 4; ++c) {
            float s = xs[c] * invT;
            mloc = fmaxf(mloc, s);
            float q = __expf(s) * qscale;
            float t = fminf(fmaxf(s + 64.0f, 44.0f), 84.0f);
            int bin = (int)((__float_as_uint(t) - BLO) >> BSH);
            bin = min(bin, NBIN - 1);
            atomicAdd(&qmass[bin], q);
        }
    }
    #pragma unroll
    for (int o = 32; o > 0; o >>= 1) mloc = fmaxf(mloc, __shfl_down(mloc, o, 64));
    if ((tid & 63) == 0) wred[tid >> 6] = mloc;
    __syncthreads();
    if (tid < 16) {
        float vv = wred[tid];
        #pragma unroll
        for (int o = 8; o > 0; o >>= 1) vv = fmaxf(vv, __shfl_down(vv, o, 16));
        if (tid == 0) sh_m = vv;
    }
    __syncthreads();
    const float m = sh_m;

    const int b0 = tid * NCH;
    float chs = 0.0f;
    #pragma unroll
    for (int i2 = 0; i2 < NCH; ++i2) {
        int b = b0 + i2;
        if (b < NBIN) chs += qmass[b];
    }
    ct[tid] = chs;
    __syncthreads();
    float* src = ct; float* dst = ct2;
    for (int d = 1; d < ONT; d <<= 1) {
        float val = src[tid] + ((tid + d < ONT) ? src[tid + d] : 0.0f);
        dst[tid] = val;
        __syncthreads();
        float* tm = src; src = dst; dst = tm;
    }
    const float Zq = src[0];
    const float P = topp * Zq;
    {
        float mine = src[tid];
        float nxt = (tid + 1 < ONT) ? src[tid + 1] : 0.0f;
        if (mine > P && nxt <= P)
            atomicMax(&sh_cross, ((unsigned long long)(tid + 1) << 32));
    }
    __syncthreads();
    if (tid == 0) {
        sh_Zq = Zq;
        if (sh_cross == 0ull) { sh_bstar = -1000000; sh_A = 0.0f; }
        else {
            int cstar = (int)(sh_cross >> 32) - 1;
            float run = (cstar + 1 < ONT) ? src[cstar + 1] : 0.0f;
            int bst = -1; float abv = run;
            for (int i2 = NCH - 1; i2 >= 0; --i2) {
                int b = cstar * NCH + i2;
                if (b >= NBIN) continue;
                float inc = qmass[b];
                if (run <= P && run + inc > P) { bst = b; abv = run; break; }
                run += inc;
            }
            if (bst < 0) { bst = cstar * NCH; abv = run; }
            sh_bstar = bst;
            float A = abv;
            if (bst + 1 < NBIN) A -= qmass[bst + 1];
            if (A < 0.0f) A = 0.0f;
            sh_A = A;
        }
    }
    __syncthreads();

    const int bstar = sh_bstar;
    const float Zrow = sh_Zq * 1048576.0f * __expf(-m);
    const float invZrow = 1.0f / Zrow;

    const float4* __restrict__ u4 = (const float4*)urow;
    unsigned long long mybest = 0ull;
    for (int v = tid; v < NV4; v += ONT) {
        float4 x = l4[v];
        float4 uu = u4[v];
        float xs[4] = {x.x, x.y, x.z, x.w};
        float us[4] = {uu.x, uu.y, uu.z, uu.w};
        #pragma unroll
        for (int c = 0; c < 4; ++c) {
            float s = xs[c] * invT;
            float t = fminf(fmaxf(s + 64.0f, 44.0f), 84.0f);
            int bin = (int)((__float_as_uint(t) - BLO) >> BSH);
            bin = min(bin, NBIN - 1);
            if (bin >= bstar + 2) {
                float e = __expf(s - m);
                float noise = fmaxf(-__logf(us[c]), 1e-10f);
                float r = __fdividef(e * invZrow, noise);
                int i = v * 4 + c;
                unsigned long long key = ((unsigned long long)__float_as_uint(r) << 32)
                                       | (unsigned long long)(0xFFFFFFFFu - (unsigned)i);
                if (key > mybest) mybest = key;
            } else if (bin >= bstar - 1) {
                float e = __expf(s - m);
                float p = e / Zrow;
                int i = v * 4 + c;
                unsigned int pos = atomicAdd(&gcnt, 1u);
                if (pos < GCAP)
                    gkeys[pos] = ((unsigned long long)__float_as_uint(p) << 32)
                               | (unsigned long long)(0xFFFFFFFFu - (unsigned)i);
            }
        }
    }
    atomicMax(&sh_best, mybest);
    __syncthreads();

    unsigned int ngu = gcnt; if (ngu > GCAP) ngu = GCAP;
    const int ng = (int)ngu;
    for (int i = tid; i < GCAP; i += ONT) if (i >= ng) gkeys[i] = 0ull;
    __syncthreads();
    if (ng > 0) {
        for (int k = 2; k <= GCAP; k <<= 1) {
            for (int j = k >> 1; j > 0; j >>= 1) {
                for (int i = tid; i < GCAP; i += ONT) {
                    int ixj = i ^ j;
                    if (ixj > i) {
                        unsigned long long a = gkeys[i], b = gkeys[ixj];
                        bool up = ((i & k) == 0);
                        bool sw = up ? (a < b) : (a > b);
                        if (sw) { gkeys[i] = b; gkeys[ixj] = a; }
                    }
                }
                __syncthreads();
            }
        }
        for (int i = tid; i < GCAP; i += ONT)
            sa[i] = __uint_as_float((unsigned)(gkeys[i] >> 32));
        __syncthreads();
        float* ssrc = sa; float* sdst = sb;
        for (int d = 1; d < GCAP; d <<= 1) {
            for (int i = tid; i < GCAP; i += ONT)
                sdst[i] = ssrc[i] + ((i >= d) ? ssrc[i - d] : 0.0f);
            __syncthreads();
            float* tm = ssrc; ssrc = sdst; sdst = tm;
        }
        const float A_p = sh_A / sh_Zq;
        for (int i = tid; i < GCAP; i += ONT) {
            if (i < ng) {
                float excl = (i == 0) ? A_p : (A_p + ssrc[i - 1]);
                if (excl <= topp) atomicMax(&sh_kstar, i + 1);
            }
        }
        __syncthreads();
        const int kst = sh_kstar;
        unsigned long long gb = 0ull;
        for (int i = tid; i < kst; i += ONT) {
            unsigned long long key = gkeys[i];
            unsigned int idx = 0xFFFFFFFFu - (unsigned)(key & 0xFFFFFFFFull);
            float p = __uint_as_float((unsigned)(key >> 32));
            float u = urow[idx];
            float noise = fmaxf(-__logf(u), 1e-10f);
            float r = __fdividef(p, noise);
            unsigned long long k2 = ((unsigned long long)__float_as_uint(r) << 32)
                                  | (unsigned long long)(0xFFFFFFFFu - idx);
            if (k2 > gb) gb = k2;
        }
        atomicMax(&sh_best, gb);
        __syncthreads();
    }
    if (tid == 0) {
        unsigned long long kk = sh_best;
        out[row] = (int)(0xFFFFFFFFu - (unsigned)(kk & 0xFFFFFFFFull));
    }
}

extern "C" void kernel_launch(void* const* d_in, const int* in_sizes, int n_in,
                              void* d_out, int out_size, void* d_ws, size_t ws_size,
                              hipStream_t stream) {
    const float* logits = (const float*)d_in[0];
    const float* temps  = (const float*)d_in[1];
    const float* topps  = (const float*)d_in[2];
    const float* unoise = (const float*)d_in[3];
    int* out = (int*)d_out;

    if (ws_size < WS_NEEDED) {
        hipLaunchKernelGGL(sampler_fallback, dim3(NROW), dim3(ONT), 0, stream,
                           logits, temps, topps, unoise, out);
        return;
    }

    RowParams* params = (RowParams*)d_ws;
    hipLaunchKernelGGL(kA_hist_scan, dim3(NROW), dim3(TPB), 0, stream,
                       logits, temps, topps, params);
    hipLaunchKernelGGL(kB_race_select, dim3(NROW), dim3(TPB), 0, stream,
                       logits, temps, unoise, params, out);
}